// Round 6
// baseline (378.727 us; speedup 1.0000x reference)
//
#include <hip/hip_runtime.h>
#include <hip/hip_bf16.h>
#include <stdint.h>

// ---------------------------------------------------------------------------
// MHA: B=2, S=4096, D=512, H=8, dk=64.
// R6: flash VALU diet. Register-only K-loop (C->B layout identity, pi-permuted
// V), XCD-clustered (bh = id&7 -> 2MB K/V per XCD L2), 3-slot rotating
// pipeline with immediate-offset addressing (per-slot int offset += 6144),
// hoisted zero accumulator, v_cvt_pk_bf16_f32 packing via
// __float22bfloat162_rn. No LDS, no barriers in flash.
// ---------------------------------------------------------------------------

typedef float  floatx4 __attribute__((ext_vector_type(4)));
typedef __bf16 bf16x8  __attribute__((ext_vector_type(8)));
typedef short  shortx4 __attribute__((ext_vector_type(4)));

#define MFMA16(a, b, c) __builtin_amdgcn_mfma_f32_16x16x32_bf16((a), (b), (c), 0, 0, 0)

// folded into Q projection: (1/sqrt(64)) * log2(e)  -> scores in log2 domain
#define QSCALE 0.1803368801111244f

__device__ __forceinline__ short f2bf(float f) {   // RNE (scalar fallback path)
  union { float f; uint32_t u; } a; a.f = f;
  uint32_t u = a.u;
  u += 0x7fffu + ((u >> 16) & 1u);
  return (short)(u >> 16);
}

// ---------------------------------------------------------------------------
// fp32 -> bf16 activations (q,k,v), blockIdx.y picks tensor
// ---------------------------------------------------------------------------
__global__ __launch_bounds__(256) void cvt3_kernel(const float* __restrict__ q,
                                                   const float* __restrict__ k,
                                                   const float* __restrict__ v,
                                                   short* __restrict__ out, int n4) {
  const int which = blockIdx.y;
  const float* in = which == 0 ? q : which == 1 ? k : v;
  short* o = out + (size_t)which * (size_t)n4 * 4;
  int i = blockIdx.x * 256 + threadIdx.x;
  if (i < n4) {
    float4 f = reinterpret_cast<const float4*>(in)[i];
    shortx4 s;
    s.x = f2bf(f.x); s.y = f2bf(f.y); s.z = f2bf(f.z); s.w = f2bf(f.w);
    reinterpret_cast<shortx4*>(o)[i] = s;
  }
}

// weights fp32 -> bf16, blockIdx.y picks tensor
__global__ __launch_bounds__(256) void cvtw_kernel(const float* __restrict__ w0,
                                                   const float* __restrict__ w1,
                                                   const float* __restrict__ w2,
                                                   const float* __restrict__ w3,
                                                   short* __restrict__ out, int n4) {
  const int which = blockIdx.y;
  const float* in = which == 0 ? w0 : which == 1 ? w1 : which == 2 ? w2 : w3;
  short* o = out + (size_t)which * (size_t)n4 * 4;
  int i = blockIdx.x * 256 + threadIdx.x;
  if (i < n4) {
    float4 f = reinterpret_cast<const float4*>(in)[i];
    shortx4 s;
    s.x = f2bf(f.x); s.y = f2bf(f.y); s.z = f2bf(f.z); s.w = f2bf(f.w);
    reinterpret_cast<shortx4*>(o)[i] = s;
  }
}

// ---------------------------------------------------------------------------
// Fused Q/K/V projection. blockIdx.z picks tensor. A[8192,512] x W[512,512]^T.
// Wave = 32 rows x 64 cols (2 m-tiles x 4 n-tiles = 8 MFMA / 6 loads per kk).
// Q out: [bh][s][64] * QSCALE. K out: [bh][s][64].
// V out: permuted-transposed [bh][g=s>>5][d][l], l = pi^-1(s&31).
// ---------------------------------------------------------------------------
__global__ __launch_bounds__(256) void proj3_kernel(
    const short* __restrict__ xq, const short* __restrict__ xk, const short* __restrict__ xv,
    const short* __restrict__ wq, const short* __restrict__ wk, const short* __restrict__ wv,
    const float* __restrict__ bq, const float* __restrict__ bk, const float* __restrict__ bv,
    short* __restrict__ Qh, short* __restrict__ Kh, short* __restrict__ Vt) {
  const int which = blockIdx.z;
  const short* A = which == 0 ? xq : which == 1 ? xk : xv;
  const short* W = which == 0 ? wq : which == 1 ? wk : wv;
  const float* bias = which == 0 ? bq : which == 1 ? bk : bv;
  const float scale = which == 0 ? QSCALE : 1.0f;

  const int K = 512;
  const int lane = threadIdx.x & 63;
  const int wave = threadIdx.x >> 6;
  const int l15 = lane & 15;
  const int quad = lane >> 4;
  const int tileM = blockIdx.x * 128;
  const int tileN = blockIdx.y * 64;

  const short* Ap0 = A + (size_t)(tileM + wave * 32 + l15) * K + quad * 8;
  const short* Ap1 = Ap0 + (size_t)16 * K;
  const short* Wp = W + (size_t)(tileN + l15) * K + quad * 8;

  floatx4 acc[2][4];
#pragma unroll
  for (int mt = 0; mt < 2; ++mt)
#pragma unroll
    for (int nt = 0; nt < 4; ++nt) acc[mt][nt] = (floatx4){0.f, 0.f, 0.f, 0.f};

  for (int kk = 0; kk < K; kk += 32) {
    bf16x8 af0 = *(const bf16x8*)(Ap0 + kk);
    bf16x8 af1 = *(const bf16x8*)(Ap1 + kk);
#pragma unroll
    for (int nt = 0; nt < 4; ++nt) {
      bf16x8 wf = *(const bf16x8*)(Wp + (size_t)nt * 16 * K + kk);
      acc[0][nt] = MFMA16(af0, wf, acc[0][nt]);
      acc[1][nt] = MFMA16(af1, wf, acc[1][nt]);
    }
  }

#pragma unroll
  for (int mt = 0; mt < 2; ++mt) {
    const int rowbase = tileM + wave * 32 + mt * 16 + quad * 4;  // row = quad*4+reg
    if (which < 2) {
      short* out = which == 0 ? Qh : Kh;
#pragma unroll
      for (int nt = 0; nt < 4; ++nt) {
        const int col = tileN + nt * 16 + l15;
        const int h = col >> 6, d = col & 63;
        const float bc = bias[col];
#pragma unroll
        for (int r = 0; r < 4; ++r) {
          const int row = rowbase + r;
          const int b = row >> 12, s = row & 4095;
          out[(size_t)((b * 8 + h) * 4096 + s) * 64 + d] = f2bf((acc[mt][nt][r] + bc) * scale);
        }
      }
    } else {
      const int b = rowbase >> 12, s = rowbase & 4095;
      const int g = s >> 5;
      const int p32 = s & 31;                               // multiple of 4
      const int l0 = ((p32 & 15) >> 2) * 8 + (p32 >> 4) * 4;  // logical base; +r contiguous
#pragma unroll
      for (int nt = 0; nt < 4; ++nt) {
        const int col = tileN + nt * 16 + l15;
        const int h = col >> 6, d = col & 63;
        const float bc = bias[col];
        shortx4 p;
        p.x = f2bf(acc[mt][nt][0] + bc);
        p.y = f2bf(acc[mt][nt][1] + bc);
        p.z = f2bf(acc[mt][nt][2] + bc);
        p.w = f2bf(acc[mt][nt][3] + bc);
        const size_t idx = (size_t)(b * 8 + h) * 262144 + (size_t)g * 2048 +
                           (size_t)d * 32 + l0;
        *(shortx4*)(Vt + idx) = p;
      }
    }
  }
}

// ---------------------------------------------------------------------------
// Output projection: ctx bf16 [8192,512] x Wo^T + bo -> fp32 out.
// ---------------------------------------------------------------------------
__global__ __launch_bounds__(256) void proj_o_kernel(
    const short* __restrict__ A, const short* __restrict__ W,
    const float* __restrict__ bias, float* __restrict__ out) {
  const int K = 512;
  const int lane = threadIdx.x & 63;
  const int wave = threadIdx.x >> 6;
  const int l15 = lane & 15;
  const int quad = lane >> 4;
  const int tileM = blockIdx.x * 128;
  const int tileN = blockIdx.y * 64;

  const short* Ap0 = A + (size_t)(tileM + wave * 32 + l15) * K + quad * 8;
  const short* Ap1 = Ap0 + (size_t)16 * K;
  const short* Wp = W + (size_t)(tileN + l15) * K + quad * 8;

  floatx4 acc[2][4];
#pragma unroll
  for (int mt = 0; mt < 2; ++mt)
#pragma unroll
    for (int nt = 0; nt < 4; ++nt) acc[mt][nt] = (floatx4){0.f, 0.f, 0.f, 0.f};

  for (int kk = 0; kk < K; kk += 32) {
    bf16x8 af0 = *(const bf16x8*)(Ap0 + kk);
    bf16x8 af1 = *(const bf16x8*)(Ap1 + kk);
#pragma unroll
    for (int nt = 0; nt < 4; ++nt) {
      bf16x8 wf = *(const bf16x8*)(Wp + (size_t)nt * 16 * K + kk);
      acc[0][nt] = MFMA16(af0, wf, acc[0][nt]);
      acc[1][nt] = MFMA16(af1, wf, acc[1][nt]);
    }
  }

#pragma unroll
  for (int mt = 0; mt < 2; ++mt) {
    const int rowbase = tileM + wave * 32 + mt * 16 + quad * 4;
#pragma unroll
    for (int nt = 0; nt < 4; ++nt) {
      const int col = tileN + nt * 16 + l15;
      const float bc = bias[col];
#pragma unroll
      for (int r = 0; r < 4; ++r) out[(size_t)(rowbase + r) * 512 + col] = acc[mt][nt][r] + bc;
    }
  }
}

// ---------------------------------------------------------------------------
// Register-only flash, XCD-clustered, 3-slot pipeline, immediate offsets.
// Qh/Kh: [bh][s][64] bf16 (Q scaled, log2 domain). Vt: [bh][g][d][l] permuted.
// 1-D grid of 512 blocks; xcd = id&7; each XCD covers bh {xcd, xcd+8} only.
// Wave = 32 qrows x 4096 keys (128 groups of 32).
// Per group g: K frag addr = Kb + g*2048 + koff + {0,32,1024,1056},
//              V frag addr = Vb + g*2048 + voff + {0,512,1024,1536}  (shorts).
// ---------------------------------------------------------------------------
__global__ __launch_bounds__(256) void flash_kernel(
    const short* __restrict__ Qh, const short* __restrict__ Kh,
    const short* __restrict__ Vt, short* __restrict__ ctx) {
  const int id = blockIdx.x;          // 0..511
  const int xcd = id & 7;
  const int j = id >> 3;              // 0..63
  const int bh = xcd + ((j >> 5) << 3);
  const int qtile = j & 31;

  const int tid = threadIdx.x;
  const int wave = tid >> 6;
  const int lane = tid & 63;
  const int l15 = lane & 15;
  const int quad = lane >> 4;
  const int qrow0 = qtile * 128 + wave * 32;

  // Q B-frags: B[k=d=quad*8+i+32kstep][n=qrow=l15]
  bf16x8 qf[2][2];
#pragma unroll
  for (int nt = 0; nt < 2; ++nt) {
    const short* Qb = Qh + (size_t)(bh * 4096 + qrow0 + nt * 16 + l15) * 64 + quad * 8;
    qf[nt][0] = *(const bf16x8*)(Qb);
    qf[nt][1] = *(const bf16x8*)(Qb + 32);
  }

  const short* Kb = Kh + (size_t)bh * 262144;
  const short* Vb = Vt + (size_t)bh * 262144;
  const int koff = l15 * 64 + quad * 8;
  const int voff = l15 * 32 + quad * 8;

  const floatx4 FZ = (floatx4){0.f, 0.f, 0.f, 0.f};  // hoisted zero accumulator

  floatx4 o[2][4];
  float l[2] = {0.f, 0.f};
#pragma unroll
  for (int nt = 0; nt < 2; ++nt)
#pragma unroll
    for (int dt = 0; dt < 4; ++dt) o[nt][dt] = FZ;

  // rotating 3-slot buffers (load-use distance = 2 phases)
  bf16x8 ka0[2][2], vf0[4], ka1[2][2], vf1[4], ka2[2][2], vf2[4];

#define LOADG(KA, VF, OFF) do {                                     \
    const short* kp = Kb + (OFF) + koff;                            \
    KA[0][0] = *(const bf16x8*)(kp);                                \
    KA[0][1] = *(const bf16x8*)(kp + 32);                           \
    KA[1][0] = *(const bf16x8*)(kp + 1024);                         \
    KA[1][1] = *(const bf16x8*)(kp + 1056);                         \
    const short* vp = Vb + (OFF) + voff;                            \
    VF[0] = *(const bf16x8*)(vp);                                   \
    VF[1] = *(const bf16x8*)(vp + 512);                             \
    VF[2] = *(const bf16x8*)(vp + 1024);                            \
    VF[3] = *(const bf16x8*)(vp + 1536);                            \
  } while (0)

#define COMPUTE(KA, VF) do {                                                    \
    floatx4 st[2][2];                                                           \
    _Pragma("unroll")                                                           \
    for (int nt = 0; nt < 2; ++nt)                                              \
      _Pragma("unroll")                                                         \
      for (int t = 0; t < 2; ++t)                                               \
        st[nt][t] = MFMA16(KA[t][1], qf[nt][1], MFMA16(KA[t][0], qf[nt][0], FZ)); \
    bf16x8 pb[2];                                                               \
    _Pragma("unroll")                                                           \
    for (int nt = 0; nt < 2; ++nt) {                                            \
      float p[8];                                                               \
      _Pragma("unroll")                                                         \
      for (int t = 0; t < 2; ++t)                                               \
        _Pragma("unroll")                                                       \
        for (int r = 0; r < 4; ++r) p[t * 4 + r] = __builtin_amdgcn_exp2f(st[nt][t][r]); \
    l[nt] += ((p[0] + p[1]) + (p[2] + p[3])) + ((p[4] + p[5]) + (p[6] + p[7])); \
      union { __hip_bfloat162 h2[4]; bf16x8 v8; } u;                            \
      u.h2[0] = __float22bfloat162_rn(float2{p[0], p[1]});                      \
      u.h2[1] = __float22bfloat162_rn(float2{p[2], p[3]});                      \
      u.h2[2] = __float22bfloat162_rn(float2{p[4], p[5]});                      \
      u.h2[3] = __float22bfloat162_rn(float2{p[6], p[7]});                      \
      pb[nt] = u.v8;                                                            \
    }                                                                           \
    _Pragma("unroll")                                                           \
    for (int nt = 0; nt < 2; ++nt)                                              \
      _Pragma("unroll")                                                         \
      for (int dt = 0; dt < 4; ++dt)                                            \
        o[nt][dt] = MFMA16(VF[dt], pb[nt], o[nt][dt]);                          \
  } while (0)

  int o0 = 0, o1 = 2048, o2 = 4096;   // slot group-offsets (shorts)
  LOADG(ka0, vf0, o0);
  LOADG(ka1, vf1, o1);
  for (int k3 = 0; k3 < 42; ++k3) {
    LOADG(ka2, vf2, o2);
    COMPUTE(ka0, vf0);
    o0 += 6144;
    LOADG(ka0, vf0, o0);
    COMPUTE(ka1, vf1);
    o1 += 6144;
    LOADG(ka1, vf1, o1);
    COMPUTE(ka2, vf2);
    o2 += 6144;
  }
  COMPUTE(ka0, vf0);   // group 126
  COMPUTE(ka1, vf1);   // group 127

#undef LOADG
#undef COMPUTE

  // epilogue: l lives per-lane for qrow=l15; reduce across the 4 quads
  const int b = bh >> 3, h = bh & 7;
#pragma unroll
  for (int nt = 0; nt < 2; ++nt) {
    float ls = l[nt];
    ls += __shfl_xor(ls, 16, 64);
    ls += __shfl_xor(ls, 32, 64);
    const float inv = 1.0f / ls;
    const int row = qrow0 + nt * 16 + l15;
    short* cp = ctx + (size_t)(b * 4096 + row) * 512 + h * 64 + quad * 4;
#pragma unroll
    for (int dt = 0; dt < 4; ++dt) {
      union { __hip_bfloat162 h2[2]; shortx4 s4; } u;
      u.h2[0] = __float22bfloat162_rn(float2{o[nt][dt][0] * inv, o[nt][dt][1] * inv});
      u.h2[1] = __float22bfloat162_rn(float2{o[nt][dt][2] * inv, o[nt][dt][3] * inv});
      *(shortx4*)(cp + dt * 16) = u.s4;
    }
  }
}

// ---------------------------------------------------------------------------
extern "C" void kernel_launch(void* const* d_in, const int* in_sizes, int n_in,
                              void* d_out, int out_size, void* d_ws, size_t ws_size,
                              hipStream_t stream) {
  const float* q  = (const float*)d_in[0];
  const float* k  = (const float*)d_in[1];
  const float* v  = (const float*)d_in[2];
  const float* Wq = (const float*)d_in[3];
  const float* bq = (const float*)d_in[4];
  const float* Wk = (const float*)d_in[5];
  const float* bk = (const float*)d_in[6];
  const float* Wv = (const float*)d_in[7];
  const float* bv = (const float*)d_in[8];
  const float* Wo = (const float*)d_in[9];
  const float* bo = (const float*)d_in[10];

  const int XN = 2 * 4096 * 512;
  const int WN = 512 * 512;

  short* ws  = (short*)d_ws;
  short* xqb = ws;                       // q/k/v bf16 (contiguous for cvt3)
  short* xkb = ws + (size_t)XN;
  short* xvb = ws + (size_t)2 * XN;
  short* wqb = ws + (size_t)3 * XN;      // weights bf16 (contiguous for cvtw)
  short* wkb = wqb + WN;
  short* wvb = wkb + WN;
  short* wob = wvb + WN;
  short* Qh  = wob + WN;
  short* Kh  = Qh + (size_t)XN;
  short* Vt  = Kh + (size_t)XN;
  short* ctx = xqb;                      // xq dead after projections

  dim3 cg(XN / 4 / 256, 3);
  cvt3_kernel<<<cg, 256, 0, stream>>>(q, k, v, xqb, XN / 4);
  dim3 wg(WN / 4 / 256, 4);
  cvtw_kernel<<<wg, 256, 0, stream>>>(Wq, Wk, Wv, Wo, wqb, WN / 4);

  dim3 pg(64, 8, 3);
  proj3_kernel<<<pg, 256, 0, stream>>>(xqb, xkb, xvb, wqb, wkb, wvb,
                                       bq, bk, bv, Qh, Kh, Vt);

  flash_kernel<<<512, 256, 0, stream>>>(Qh, Kh, Vt, ctx);

  dim3 og(64, 8);
  proj_o_kernel<<<og, 256, 0, stream>>>(ctx, wob, bo, (float*)d_out);
}

// Round 8
// 291.231 us; speedup vs baseline: 1.3004x; 1.3004x over previous
//
#include <hip/hip_runtime.h>
#include <hip/hip_bf16.h>
#include <stdint.h>

// ---------------------------------------------------------------------------
// MHA: B=2, S=4096, D=512, H=8, dk=64.
// R8: flash stages K/V once per BLOCK into DOUBLE-BUFFERED LDS (2x8KB) via
// global_load_lds; one __syncthreads per 32-key group + explicit vmcnt(0)
// drain (race-free by construction: staging targets the opposite buffer).
// K/V in global are fragment-ordered (written by proj3) so staging is a
// linear 16B/lane memcpy and fragment ds_read_b128s are conflict-free.
// Softmax: fixed-base exp2 (log2-domain scores), sums deferred to epilogue.
// ---------------------------------------------------------------------------

typedef float  floatx4 __attribute__((ext_vector_type(4)));
typedef __bf16 bf16x8  __attribute__((ext_vector_type(8)));
typedef short  shortx4 __attribute__((ext_vector_type(4)));

#define MFMA16(a, b, c) __builtin_amdgcn_mfma_f32_16x16x32_bf16((a), (b), (c), 0, 0, 0)

// folded into Q projection: (1/sqrt(64)) * log2(e)  -> scores in log2 domain
#define QSCALE 0.1803368801111244f

__device__ __forceinline__ short f2bf(float f) {   // RNE
  union { float f; uint32_t u; } a; a.f = f;
  uint32_t u = a.u;
  u += 0x7fffu + ((u >> 16) & 1u);
  return (short)(u >> 16);
}

// async global->LDS, 16B per lane; lds dest = wave-uniform base + lane*16
__device__ __forceinline__ void stage16(const short* g, short* l) {
  __builtin_amdgcn_global_load_lds(
      (const __attribute__((address_space(1))) void*)g,
      (__attribute__((address_space(3))) void*)l, 16, 0, 0);
}

// ---------------------------------------------------------------------------
// fp32 -> bf16 activations (q,k,v), blockIdx.y picks tensor
// ---------------------------------------------------------------------------
__global__ __launch_bounds__(256) void cvt3_kernel(const float* __restrict__ q,
                                                   const float* __restrict__ k,
                                                   const float* __restrict__ v,
                                                   short* __restrict__ out, int n4) {
  const int which = blockIdx.y;
  const float* in = which == 0 ? q : which == 1 ? k : v;
  short* o = out + (size_t)which * (size_t)n4 * 4;
  int i = blockIdx.x * 256 + threadIdx.x;
  if (i < n4) {
    float4 f = reinterpret_cast<const float4*>(in)[i];
    shortx4 s;
    s.x = f2bf(f.x); s.y = f2bf(f.y); s.z = f2bf(f.z); s.w = f2bf(f.w);
    reinterpret_cast<shortx4*>(o)[i] = s;
  }
}

// weights fp32 -> bf16, blockIdx.y picks tensor
__global__ __launch_bounds__(256) void cvtw_kernel(const float* __restrict__ w0,
                                                   const float* __restrict__ w1,
                                                   const float* __restrict__ w2,
                                                   const float* __restrict__ w3,
                                                   short* __restrict__ out, int n4) {
  const int which = blockIdx.y;
  const float* in = which == 0 ? w0 : which == 1 ? w1 : which == 2 ? w2 : w3;
  short* o = out + (size_t)which * (size_t)n4 * 4;
  int i = blockIdx.x * 256 + threadIdx.x;
  if (i < n4) {
    float4 f = reinterpret_cast<const float4*>(in)[i];
    shortx4 s;
    s.x = f2bf(f.x); s.y = f2bf(f.y); s.z = f2bf(f.z); s.w = f2bf(f.w);
    reinterpret_cast<shortx4*>(o)[i] = s;
  }
}

// ---------------------------------------------------------------------------
// Fused Q/K/V projection. blockIdx.z picks tensor. A[8192,512] x W[512,512]^T.
// Wave = 32 rows x 64 cols (2 m-tiles x 4 n-tiles = 8 MFMA / 6 loads per kk).
// Q out: [bh][s][64] * QSCALE.
// K/V out: fragment-ordered KV buffer. Per (bh, g) an 8KB block (4096 shorts):
//   K chunk (t,ks,l15,quad) at ((t*2+ks)*64 + l15*4 + quad)*8 + j
//     holds K[key=t*16+l15][d=ks*32+quad*8+j]
//   V chunk at 2048 + (dt*64 + l15*4 + quad)*8 + j
//     holds V^T[d=dt*16+l15][l=quad*8+j], l = pi(p) = ((p&15)>>2)*8+(p>>4)*4+(p&3)
// ---------------------------------------------------------------------------
__global__ __launch_bounds__(256) void proj3_kernel(
    const short* __restrict__ xq, const short* __restrict__ xk, const short* __restrict__ xv,
    const short* __restrict__ wq, const short* __restrict__ wk, const short* __restrict__ wv,
    const float* __restrict__ bq, const float* __restrict__ bk, const float* __restrict__ bv,
    short* __restrict__ Qh, short* __restrict__ KV) {
  const int which = blockIdx.z;
  const short* A = which == 0 ? xq : which == 1 ? xk : xv;
  const short* W = which == 0 ? wq : which == 1 ? wk : wv;
  const float* bias = which == 0 ? bq : which == 1 ? bk : bv;

  const int K = 512;
  const int lane = threadIdx.x & 63;
  const int wave = threadIdx.x >> 6;
  const int l15 = lane & 15;
  const int quad = lane >> 4;
  const int tileM = blockIdx.x * 128;
  const int tileN = blockIdx.y * 64;

  const short* Ap0 = A + (size_t)(tileM + wave * 32 + l15) * K + quad * 8;
  const short* Ap1 = Ap0 + (size_t)16 * K;
  const short* Wp = W + (size_t)(tileN + l15) * K + quad * 8;

  floatx4 acc[2][4];
#pragma unroll
  for (int mt = 0; mt < 2; ++mt)
#pragma unroll
    for (int nt = 0; nt < 4; ++nt) acc[mt][nt] = (floatx4){0.f, 0.f, 0.f, 0.f};

  for (int kk = 0; kk < K; kk += 32) {
    bf16x8 af0 = *(const bf16x8*)(Ap0 + kk);
    bf16x8 af1 = *(const bf16x8*)(Ap1 + kk);
#pragma unroll
    for (int nt = 0; nt < 4; ++nt) {
      bf16x8 wf = *(const bf16x8*)(Wp + (size_t)nt * 16 * K + kk);
      acc[0][nt] = MFMA16(af0, wf, acc[0][nt]);
      acc[1][nt] = MFMA16(af1, wf, acc[1][nt]);
    }
  }

#pragma unroll
  for (int mt = 0; mt < 2; ++mt) {
    const int rowbase = tileM + wave * 32 + mt * 16 + quad * 4;  // C/D row = quad*4+reg
    const int b = rowbase >> 12, s = rowbase & 4095;
    const int g = s >> 5;
    if (which == 0) {
      // Q: [bh][s][64], scaled into log2 domain
#pragma unroll
      for (int nt = 0; nt < 4; ++nt) {
        const int col = tileN + nt * 16 + l15;
        const int h = col >> 6, d = col & 63;
        const float bc = bias[col];
#pragma unroll
        for (int r = 0; r < 4; ++r) {
          const int row = rowbase + r;
          const int ss = row & 4095;
          Qh[(size_t)((b * 8 + h) * 4096 + ss) * 64 + d] = f2bf((acc[mt][nt][r] + bc) * QSCALE);
        }
      }
    } else if (which == 1) {
      // K fragment chunks
      const int key = s & 31;
      const int t = key >> 4;
      const int l15b = key & 15;                 // +r, stays <16
#pragma unroll
      for (int nt = 0; nt < 4; ++nt) {
        const int col = tileN + nt * 16 + l15;
        const int h = col >> 6, dd = col & 63;
        const int ks = dd >> 5, quadk = (dd >> 3) & 3, jj = dd & 7;
        const float bc = bias[col];
        const size_t base = ((size_t)(b * 8 + h) * 128 + g) * 4096 +
                            (size_t)(t * 2 + ks) * 512 + (size_t)quadk * 8 + jj;
#pragma unroll
        for (int r = 0; r < 4; ++r)
          KV[base + (size_t)(l15b + r) * 32] = f2bf(acc[mt][nt][r] + bc);
      }
    } else {
      // V fragment chunks (pi-permuted key order), r=0..3 contiguous
      const int p32 = s & 31;                    // multiple of 4
      const int l0 = ((p32 & 15) >> 2) * 8 + (p32 >> 4) * 4;
      const int quadv = l0 >> 3, jv = l0 & 7;    // jv in {0,4}
#pragma unroll
      for (int nt = 0; nt < 4; ++nt) {
        const int col = tileN + nt * 16 + l15;
        const int h = col >> 6, dd = col & 63;
        const int dt = dd >> 4, l15v = dd & 15;
        const float bc = bias[col];
        shortx4 p;
        p.x = f2bf(acc[mt][nt][0] + bc);
        p.y = f2bf(acc[mt][nt][1] + bc);
        p.z = f2bf(acc[mt][nt][2] + bc);
        p.w = f2bf(acc[mt][nt][3] + bc);
        *(shortx4*)(KV + ((size_t)(b * 8 + h) * 128 + g) * 4096 + 2048 +
                    (size_t)(dt * 64 + l15v * 4 + quadv) * 8 + jv) = p;
      }
    }
  }
}

// ---------------------------------------------------------------------------
// Output projection: ctx bf16 [8192,512] x Wo^T + bo -> fp32 out.
// ---------------------------------------------------------------------------
__global__ __launch_bounds__(256) void proj_o_kernel(
    const short* __restrict__ A, const short* __restrict__ W,
    const float* __restrict__ bias, float* __restrict__ out) {
  const int K = 512;
  const int lane = threadIdx.x & 63;
  const int wave = threadIdx.x >> 6;
  const int l15 = lane & 15;
  const int quad = lane >> 4;
  const int tileM = blockIdx.x * 128;
  const int tileN = blockIdx.y * 64;

  const short* Ap0 = A + (size_t)(tileM + wave * 32 + l15) * K + quad * 8;
  const short* Ap1 = Ap0 + (size_t)16 * K;
  const short* Wp = W + (size_t)(tileN + l15) * K + quad * 8;

  floatx4 acc[2][4];
#pragma unroll
  for (int mt = 0; mt < 2; ++mt)
#pragma unroll
    for (int nt = 0; nt < 4; ++nt) acc[mt][nt] = (floatx4){0.f, 0.f, 0.f, 0.f};

  for (int kk = 0; kk < K; kk += 32) {
    bf16x8 af0 = *(const bf16x8*)(Ap0 + kk);
    bf16x8 af1 = *(const bf16x8*)(Ap1 + kk);
#pragma unroll
    for (int nt = 0; nt < 4; ++nt) {
      bf16x8 wf = *(const bf16x8*)(Wp + (size_t)nt * 16 * K + kk);
      acc[0][nt] = MFMA16(af0, wf, acc[0][nt]);
      acc[1][nt] = MFMA16(af1, wf, acc[1][nt]);
    }
  }

#pragma unroll
  for (int mt = 0; mt < 2; ++mt) {
    const int rowbase = tileM + wave * 32 + mt * 16 + quad * 4;
#pragma unroll
    for (int nt = 0; nt < 4; ++nt) {
      const int col = tileN + nt * 16 + l15;
      const float bc = bias[col];
#pragma unroll
      for (int r = 0; r < 4; ++r) out[(size_t)(rowbase + r) * 512 + col] = acc[mt][nt][r] + bc;
    }
  }
}

// ---------------------------------------------------------------------------
// Flash attention, double-buffered LDS K/V staging.
// Qh: [bh][s][64] bf16 (scaled, log2 domain). KV: fragment-ordered per (bh,g).
// 512 blocks, XCD-clustered (xcd = id&7 -> bh in {xcd, xcd+8}); block = 4
// waves x 32 qrows = 128 qrows, loops all 128 key-groups.
// Per group: ONE barrier (+ explicit vmcnt(0) drain), stage g+1 into the
// OTHER 8KB buffer (no reader/writer overlap: fragment data of group g is
// consumed by MFMAs before any wave reaches the g+1 barrier), then compute.
// ---------------------------------------------------------------------------
__global__ __launch_bounds__(256) void flash_kernel(
    const short* __restrict__ Qh, const short* __restrict__ KV,
    short* __restrict__ ctx) {
  __shared__ __align__(16) short sKV[2][4096];   // 2 x 8 KB group tiles

  const int id = blockIdx.x;          // 0..511
  const int xcd = id & 7;
  const int j = id >> 3;              // 0..63
  const int bh = xcd + ((j >> 5) << 3);
  const int qtile = j & 31;

  const int tid = threadIdx.x;
  const int wave = tid >> 6;
  const int lane = tid & 63;
  const int l15 = lane & 15;
  const int quad = lane >> 4;
  const int qrow0 = qtile * 128 + wave * 32;

  // Q B-frags: B[k=d=quad*8+i+32ks][n=qrow=l15]
  bf16x8 qf[2][2];
#pragma unroll
  for (int nt = 0; nt < 2; ++nt) {
    const short* Qb = Qh + (size_t)(bh * 4096 + qrow0 + nt * 16 + l15) * 64 + quad * 8;
    qf[nt][0] = *(const bf16x8*)(Qb);
    qf[nt][1] = *(const bf16x8*)(Qb + 32);
  }

  const short* KVb = KV + (size_t)bh * (128 * 4096);
  const short* sg = KVb + wave * 1024 + lane * 8;   // staging src (this wave's slice)
  const int ldw = wave * 1024;                      // wave-uniform LDS dest offset
  const int av = (l15 * 4 + quad) * 8;              // fragment chunk address (shorts)

  const floatx4 FZ = (floatx4){0.f, 0.f, 0.f, 0.f};
  floatx4 o[2][4];
  float l[2] = {0.f, 0.f};
#pragma unroll
  for (int nt = 0; nt < 2; ++nt)
#pragma unroll
    for (int dt = 0; dt < 4; ++dt) o[nt][dt] = FZ;

  // stage group 0 into buffer 0
  stage16(sg, &sKV[0][ldw]);
  stage16(sg + 512, &sKV[0][ldw + 512]);

  for (int g = 0; g < 128; ++g) {
    asm volatile("s_waitcnt vmcnt(0)" ::: "memory");  // staging(g) landed in LDS
    __syncthreads();                                  // visible to all waves

    if (g != 127) {   // stage g+1 into the OTHER buffer; lands by next barrier
      const short* gs = sg + (g + 1) * 4096;
      short* ld = &sKV[(g + 1) & 1][ldw];
      stage16(gs, ld);
      stage16(gs + 512, ld + 512);
    }

    const short* S = sKV[g & 1];
    bf16x8 ka[2][2], vf[4];
    ka[0][0] = *(const bf16x8*)&S[av];
    ka[0][1] = *(const bf16x8*)&S[av + 512];
    ka[1][0] = *(const bf16x8*)&S[av + 1024];
    ka[1][1] = *(const bf16x8*)&S[av + 1536];
    vf[0] = *(const bf16x8*)&S[av + 2048];
    vf[1] = *(const bf16x8*)&S[av + 2560];
    vf[2] = *(const bf16x8*)&S[av + 3072];
    vf[3] = *(const bf16x8*)&S[av + 3584];

    // S^T = K Q^T : D[m=key=quad*4+r (+16t)][n=qrow=l15]
    floatx4 st[2][2];
#pragma unroll
    for (int nt = 0; nt < 2; ++nt)
#pragma unroll
      for (int t = 0; t < 2; ++t)
        st[nt][t] = MFMA16(ka[t][1], qf[nt][1], MFMA16(ka[t][0], qf[nt][0], FZ));

    // p = exp2(s); C->B identity packs both tiles into the PV B-fragment
    bf16x8 pb[2];
#pragma unroll
    for (int nt = 0; nt < 2; ++nt) {
      float p[8];
#pragma unroll
      for (int t = 0; t < 2; ++t)
#pragma unroll
        for (int r = 0; r < 4; ++r) p[t * 4 + r] = __builtin_amdgcn_exp2f(st[nt][t][r]);
      l[nt] += ((p[0] + p[1]) + (p[2] + p[3])) + ((p[4] + p[5]) + (p[6] + p[7]));
      union { __hip_bfloat162 h2[4]; bf16x8 v8; } u;
      u.h2[0] = __float22bfloat162_rn(float2{p[0], p[1]});
      u.h2[1] = __float22bfloat162_rn(float2{p[2], p[3]});
      u.h2[2] = __float22bfloat162_rn(float2{p[4], p[5]});
      u.h2[3] = __float22bfloat162_rn(float2{p[6], p[7]});
      pb[nt] = u.v8;
    }

    // O^T += V^T P^T : D[m=d=dt*16+quad*4+r][n=qrow=l15]
#pragma unroll
    for (int nt = 0; nt < 2; ++nt)
#pragma unroll
      for (int dt = 0; dt < 4; ++dt)
        o[nt][dt] = MFMA16(vf[dt], pb[nt], o[nt][dt]);
  }

  // epilogue: l per-lane for qrow=l15; reduce across the 4 quads
  const int b = bh >> 3, h = bh & 7;
#pragma unroll
  for (int nt = 0; nt < 2; ++nt) {
    float ls = l[nt];
    ls += __shfl_xor(ls, 16, 64);
    ls += __shfl_xor(ls, 32, 64);
    const float inv = 1.0f / ls;
    const int row = qrow0 + nt * 16 + l15;
    short* cp = ctx + (size_t)(b * 4096 + row) * 512 + h * 64 + quad * 4;
#pragma unroll
    for (int dt = 0; dt < 4; ++dt) {
      union { __hip_bfloat162 h2[2]; shortx4 s4; } u;
      u.h2[0] = __float22bfloat162_rn(float2{o[nt][dt][0] * inv, o[nt][dt][1] * inv});
      u.h2[1] = __float22bfloat162_rn(float2{o[nt][dt][2] * inv, o[nt][dt][3] * inv});
      *(shortx4*)(cp + dt * 16) = u.s4;
    }
  }
}

// ---------------------------------------------------------------------------
extern "C" void kernel_launch(void* const* d_in, const int* in_sizes, int n_in,
                              void* d_out, int out_size, void* d_ws, size_t ws_size,
                              hipStream_t stream) {
  const float* q  = (const float*)d_in[0];
  const float* k  = (const float*)d_in[1];
  const float* v  = (const float*)d_in[2];
  const float* Wq = (const float*)d_in[3];
  const float* bq = (const float*)d_in[4];
  const float* Wk = (const float*)d_in[5];
  const float* bk = (const float*)d_in[6];
  const float* Wv = (const float*)d_in[7];
  const float* bv = (const float*)d_in[8];
  const float* Wo = (const float*)d_in[9];
  const float* bo = (const float*)d_in[10];

  const int XN = 2 * 4096 * 512;
  const int WN = 512 * 512;

  short* ws  = (short*)d_ws;
  short* xqb = ws;                       // q/k/v bf16 (contiguous for cvt3)
  short* xkb = ws + (size_t)XN;
  short* xvb = ws + (size_t)2 * XN;
  short* wqb = ws + (size_t)3 * XN;      // weights bf16 (contiguous for cvtw)
  short* wkb = wqb + WN;
  short* wvb = wkb + WN;
  short* wob = wvb + WN;
  short* Qh  = wob + WN;
  short* KVf = Qh + (size_t)XN;          // fragment-ordered K+V: 2*XN shorts
  short* ctx = xqb;                      // xq dead after projections

  dim3 cg(XN / 4 / 256, 3);
  cvt3_kernel<<<cg, 256, 0, stream>>>(q, k, v, xqb, XN / 4);
  dim3 wg(WN / 4 / 256, 4);
  cvtw_kernel<<<wg, 256, 0, stream>>>(Wq, Wk, Wv, Wo, wqb, WN / 4);

  dim3 pg(64, 8, 3);
  proj3_kernel<<<pg, 256, 0, stream>>>(xqb, xkb, xvb, wqb, wkb, wvb,
                                       bq, bk, bv, Qh, KVf);

  flash_kernel<<<512, 256, 0, stream>>>(Qh, KVf, ctx);

  dim3 og(64, 8);
  proj_o_kernel<<<og, 256, 0, stream>>>(ctx, wob, bo, (float*)d_out);
}

// Round 9
// 286.038 us; speedup vs baseline: 1.3240x; 1.0182x over previous
//
#include <hip/hip_runtime.h>
#include <hip/hip_bf16.h>
#include <stdint.h>

// ---------------------------------------------------------------------------
// MHA: B=2, S=4096, D=512, H=8, dk=64.
// R9: flash processes 2 key-groups per iteration from quad-buffered LDS
// (2 pairs x 16KB), staged per-block via global_load_lds: two independent
// MFMA/exp2 chains per wave per iter (ILP latency hiding), 1 barrier / 64
// keys. Fragment chunks are LANE-ORDERED in global+LDS (conflict-free
// ds_read_b128). Row-sums computed on the MFMA pipe via a ones-fragment.
// Softmax: fixed-base exp2 (log2-domain scores), no max subtraction.
// ---------------------------------------------------------------------------

typedef float  floatx4 __attribute__((ext_vector_type(4)));
typedef __bf16 bf16x8  __attribute__((ext_vector_type(8)));
typedef short  shortx4 __attribute__((ext_vector_type(4)));

#define MFMA16(a, b, c) __builtin_amdgcn_mfma_f32_16x16x32_bf16((a), (b), (c), 0, 0, 0)

// folded into Q projection: (1/sqrt(64)) * log2(e)  -> scores in log2 domain
#define QSCALE 0.1803368801111244f

__device__ __forceinline__ short f2bf(float f) {   // RNE
  union { float f; uint32_t u; } a; a.f = f;
  uint32_t u = a.u;
  u += 0x7fffu + ((u >> 16) & 1u);
  return (short)(u >> 16);
}

// async global->LDS, 16B per lane; lds dest = wave-uniform base + lane*16
__device__ __forceinline__ void stage16(const short* g, short* l) {
  __builtin_amdgcn_global_load_lds(
      (const __attribute__((address_space(1))) void*)g,
      (__attribute__((address_space(3))) void*)l, 16, 0, 0);
}

// ---------------------------------------------------------------------------
// fp32 -> bf16 activations (q,k,v), blockIdx.y picks tensor
// ---------------------------------------------------------------------------
__global__ __launch_bounds__(256) void cvt3_kernel(const float* __restrict__ q,
                                                   const float* __restrict__ k,
                                                   const float* __restrict__ v,
                                                   short* __restrict__ out, int n4) {
  const int which = blockIdx.y;
  const float* in = which == 0 ? q : which == 1 ? k : v;
  short* o = out + (size_t)which * (size_t)n4 * 4;
  int i = blockIdx.x * 256 + threadIdx.x;
  if (i < n4) {
    float4 f = reinterpret_cast<const float4*>(in)[i];
    shortx4 s;
    s.x = f2bf(f.x); s.y = f2bf(f.y); s.z = f2bf(f.z); s.w = f2bf(f.w);
    reinterpret_cast<shortx4*>(o)[i] = s;
  }
}

// weights fp32 -> bf16, blockIdx.y picks tensor
__global__ __launch_bounds__(256) void cvtw_kernel(const float* __restrict__ w0,
                                                   const float* __restrict__ w1,
                                                   const float* __restrict__ w2,
                                                   const float* __restrict__ w3,
                                                   short* __restrict__ out, int n4) {
  const int which = blockIdx.y;
  const float* in = which == 0 ? w0 : which == 1 ? w1 : which == 2 ? w2 : w3;
  short* o = out + (size_t)which * (size_t)n4 * 4;
  int i = blockIdx.x * 256 + threadIdx.x;
  if (i < n4) {
    float4 f = reinterpret_cast<const float4*>(in)[i];
    shortx4 s;
    s.x = f2bf(f.x); s.y = f2bf(f.y); s.z = f2bf(f.z); s.w = f2bf(f.w);
    reinterpret_cast<shortx4*>(o)[i] = s;
  }
}

// ---------------------------------------------------------------------------
// Fused Q/K/V projection. blockIdx.z picks tensor. A[8192,512] x W[512,512]^T.
// Wave = 32 rows x 64 cols (2 m-tiles x 4 n-tiles = 8 MFMA / 6 loads per kk).
// Q out: [bh][s][64] * QSCALE.
// K/V out: fragment-ordered, LANE-ORDERED KV buffer. Per (bh,g) 8KB block:
//   K chunk for flash-lane (l15=key&15, quad=dblock) of tile (t,ks) at
//     (t*2+ks)*512 + quad*128 + l15*8  (+j)
//   V chunk for flash-lane (l15=d&15, quad=keyblock) of tile dt at
//     2048 + dt*512 + quad*128 + l15*8 (+j), keys pi-permuted:
//     l = pi(p) = ((p&15)>>2)*8 + (p>>4)*4 + (p&3)
// ---------------------------------------------------------------------------
__global__ __launch_bounds__(256) void proj3_kernel(
    const short* __restrict__ xq, const short* __restrict__ xk, const short* __restrict__ xv,
    const short* __restrict__ wq, const short* __restrict__ wk, const short* __restrict__ wv,
    const float* __restrict__ bq, const float* __restrict__ bk, const float* __restrict__ bv,
    short* __restrict__ Qh, short* __restrict__ KV) {
  const int which = blockIdx.z;
  const short* A = which == 0 ? xq : which == 1 ? xk : xv;
  const short* W = which == 0 ? wq : which == 1 ? wk : wv;
  const float* bias = which == 0 ? bq : which == 1 ? bk : bv;

  const int K = 512;
  const int lane = threadIdx.x & 63;
  const int wave = threadIdx.x >> 6;
  const int l15 = lane & 15;
  const int quad = lane >> 4;
  const int tileM = blockIdx.x * 128;
  const int tileN = blockIdx.y * 64;

  const short* Ap0 = A + (size_t)(tileM + wave * 32 + l15) * K + quad * 8;
  const short* Ap1 = Ap0 + (size_t)16 * K;
  const short* Wp = W + (size_t)(tileN + l15) * K + quad * 8;

  floatx4 acc[2][4];
#pragma unroll
  for (int mt = 0; mt < 2; ++mt)
#pragma unroll
    for (int nt = 0; nt < 4; ++nt) acc[mt][nt] = (floatx4){0.f, 0.f, 0.f, 0.f};

  for (int kk = 0; kk < K; kk += 32) {
    bf16x8 af0 = *(const bf16x8*)(Ap0 + kk);
    bf16x8 af1 = *(const bf16x8*)(Ap1 + kk);
#pragma unroll
    for (int nt = 0; nt < 4; ++nt) {
      bf16x8 wf = *(const bf16x8*)(Wp + (size_t)nt * 16 * K + kk);
      acc[0][nt] = MFMA16(af0, wf, acc[0][nt]);
      acc[1][nt] = MFMA16(af1, wf, acc[1][nt]);
    }
  }

#pragma unroll
  for (int mt = 0; mt < 2; ++mt) {
    const int rowbase = tileM + wave * 32 + mt * 16 + quad * 4;  // C/D row = quad*4+reg
    const int b = rowbase >> 12, s = rowbase & 4095;
    const int g = s >> 5;
    if (which == 0) {
      // Q: [bh][s][64], scaled into log2 domain
#pragma unroll
      for (int nt = 0; nt < 4; ++nt) {
        const int col = tileN + nt * 16 + l15;
        const int h = col >> 6, d = col & 63;
        const float bc = bias[col];
#pragma unroll
        for (int r = 0; r < 4; ++r) {
          const int row = rowbase + r;
          const int ss = row & 4095;
          Qh[(size_t)((b * 8 + h) * 4096 + ss) * 64 + d] = f2bf((acc[mt][nt][r] + bc) * QSCALE);
        }
      }
    } else if (which == 1) {
      // K fragment chunks (lane-ordered: region*512 + quadk*128 + key15*8 + j)
      const int key = s & 31;
      const int t = key >> 4;
      const int l15b = key & 15;                 // +r, stays <16
#pragma unroll
      for (int nt = 0; nt < 4; ++nt) {
        const int col = tileN + nt * 16 + l15;
        const int h = col >> 6, dd = col & 63;
        const int ks = dd >> 5, quadk = (dd >> 3) & 3, jj = dd & 7;
        const float bc = bias[col];
        const size_t base = ((size_t)(b * 8 + h) * 128 + g) * 4096 +
                            (size_t)(t * 2 + ks) * 512 + (size_t)quadk * 128 + jj;
#pragma unroll
        for (int r = 0; r < 4; ++r)
          KV[base + (size_t)(l15b + r) * 8] = f2bf(acc[mt][nt][r] + bc);
      }
    } else {
      // V fragment chunks (lane-ordered: 2048 + dt*512 + quadv*128 + d15*8 + j)
      const int p32 = s & 31;                    // multiple of 4
      const int l0 = ((p32 & 15) >> 2) * 8 + (p32 >> 4) * 4;
      const int quadv = l0 >> 3, jv = l0 & 7;    // jv in {0,4}
#pragma unroll
      for (int nt = 0; nt < 4; ++nt) {
        const int col = tileN + nt * 16 + l15;
        const int h = col >> 6, dd = col & 63;
        const int dt = dd >> 4, l15v = dd & 15;
        const float bc = bias[col];
        shortx4 p;
        p.x = f2bf(acc[mt][nt][0] + bc);
        p.y = f2bf(acc[mt][nt][1] + bc);
        p.z = f2bf(acc[mt][nt][2] + bc);
        p.w = f2bf(acc[mt][nt][3] + bc);
        *(shortx4*)(KV + ((size_t)(b * 8 + h) * 128 + g) * 4096 + 2048 +
                    (size_t)dt * 512 + (size_t)quadv * 128 + (size_t)l15v * 8 + jv) = p;
      }
    }
  }
}

// ---------------------------------------------------------------------------
// Output projection: ctx bf16 [8192,512] x Wo^T + bo -> fp32 out.
// ---------------------------------------------------------------------------
__global__ __launch_bounds__(256) void proj_o_kernel(
    const short* __restrict__ A, const short* __restrict__ W,
    const float* __restrict__ bias, float* __restrict__ out) {
  const int K = 512;
  const int lane = threadIdx.x & 63;
  const int wave = threadIdx.x >> 6;
  const int l15 = lane & 15;
  const int quad = lane >> 4;
  const int tileM = blockIdx.x * 128;
  const int tileN = blockIdx.y * 64;

  const short* Ap0 = A + (size_t)(tileM + wave * 32 + l15) * K + quad * 8;
  const short* Ap1 = Ap0 + (size_t)16 * K;
  const short* Wp = W + (size_t)(tileN + l15) * K + quad * 8;

  floatx4 acc[2][4];
#pragma unroll
  for (int mt = 0; mt < 2; ++mt)
#pragma unroll
    for (int nt = 0; nt < 4; ++nt) acc[mt][nt] = (floatx4){0.f, 0.f, 0.f, 0.f};

  for (int kk = 0; kk < K; kk += 32) {
    bf16x8 af0 = *(const bf16x8*)(Ap0 + kk);
    bf16x8 af1 = *(const bf16x8*)(Ap1 + kk);
#pragma unroll
    for (int nt = 0; nt < 4; ++nt) {
      bf16x8 wf = *(const bf16x8*)(Wp + (size_t)nt * 16 * K + kk);
      acc[0][nt] = MFMA16(af0, wf, acc[0][nt]);
      acc[1][nt] = MFMA16(af1, wf, acc[1][nt]);
    }
  }

#pragma unroll
  for (int mt = 0; mt < 2; ++mt) {
    const int rowbase = tileM + wave * 32 + mt * 16 + quad * 4;
#pragma unroll
    for (int nt = 0; nt < 4; ++nt) {
      const int col = tileN + nt * 16 + l15;
      const float bc = bias[col];
#pragma unroll
      for (int r = 0; r < 4; ++r) out[(size_t)(rowbase + r) * 512 + col] = acc[mt][nt][r] + bc;
    }
  }
}

// ---------------------------------------------------------------------------
// Flash attention: quad-buffered LDS staging, 2 key-groups per iteration.
// Qh: [bh][s][64] bf16 (scaled, log2 domain). KV: fragment/lane-ordered.
// 512 blocks, XCD-clustered (xcd = id&7 -> bh in {xcd, xcd+8}); block = 4
// waves x 32 qrows = 128 qrows; 64 iterations x 64 keys.
// Per iter: ONE __syncthreads (auto vmcnt drain), stage the NEXT 16KB pair,
// then two independent compute chains (groups 2i, 2i+1) -> ILP hides latency.
// Row-sums l accumulate on the MFMA pipe via a ones-A-fragment.
// ---------------------------------------------------------------------------
__global__ __launch_bounds__(256) void flash_kernel(
    const short* __restrict__ Qh, const short* __restrict__ KV,
    short* __restrict__ ctx) {
  __shared__ __align__(16) short sKV[2][8192];   // 2 pairs x 16 KB

  const int id = blockIdx.x;          // 0..511
  const int xcd = id & 7;
  const int j = id >> 3;              // 0..63
  const int bh = xcd + ((j >> 5) << 3);
  const int qtile = j & 31;

  const int tid = threadIdx.x;
  const int wave = tid >> 6;
  const int lane = tid & 63;
  const int l15 = lane & 15;
  const int quad = lane >> 4;
  const int qrow0 = qtile * 128 + wave * 32;

  // Q B-frags: B[k=d=quad*8+i+32ks][n=qrow=l15]
  bf16x8 qf[2][2];
#pragma unroll
  for (int nt = 0; nt < 2; ++nt) {
    const short* Qb = Qh + (size_t)(bh * 4096 + qrow0 + nt * 16 + l15) * 64 + quad * 8;
    qf[nt][0] = *(const bf16x8*)(Qb);
    qf[nt][1] = *(const bf16x8*)(Qb + 32);
  }

  // ones A-fragment (bf16 1.0 = 0x3F80) for MFMA row-sums
  bf16x8 ones;
  {
    union { short s[8]; bf16x8 v; } u;
#pragma unroll
    for (int i = 0; i < 8; ++i) u.s[i] = (short)0x3F80;
    ones = u.v;
  }

  const short* KVb = KV + (size_t)bh * (128 * 4096);
  const short* sg = KVb + wave * 1024 + lane * 8;   // staging src (wave's slice)
  const int ldw = wave * 1024;                      // wave-uniform LDS dest offset
  const int av = lane * 8;                          // lane-ordered chunk address

  const floatx4 FZ = (floatx4){0.f, 0.f, 0.f, 0.f};
  floatx4 o[2][4];
  floatx4 lacc[2];
#pragma unroll
  for (int nt = 0; nt < 2; ++nt) {
    lacc[nt] = FZ;
#pragma unroll
    for (int dt = 0; dt < 4; ++dt) o[nt][dt] = FZ;
  }

  // stage groups 0,1 into pair 0
  stage16(sg, &sKV[0][ldw]);
  stage16(sg + 512, &sKV[0][ldw + 512]);
  stage16(sg + 4096, &sKV[0][ldw + 4096]);
  stage16(sg + 4608, &sKV[0][ldw + 4608]);

#define COMPUTE(S) do {                                                         \
    bf16x8 ka[2][2], vf[4];                                                     \
    ka[0][0] = *(const bf16x8*)&(S)[av];                                        \
    ka[0][1] = *(const bf16x8*)&(S)[av + 512];                                  \
    ka[1][0] = *(const bf16x8*)&(S)[av + 1024];                                 \
    ka[1][1] = *(const bf16x8*)&(S)[av + 1536];                                 \
    vf[0] = *(const bf16x8*)&(S)[av + 2048];                                    \
    vf[1] = *(const bf16x8*)&(S)[av + 2560];                                    \
    vf[2] = *(const bf16x8*)&(S)[av + 3072];                                    \
    vf[3] = *(const bf16x8*)&(S)[av + 3584];                                    \
    floatx4 st[2][2];                                                           \
    _Pragma("unroll")                                                           \
    for (int nt = 0; nt < 2; ++nt)                                              \
      _Pragma("unroll")                                                         \
      for (int t = 0; t < 2; ++t)                                               \
        st[nt][t] = MFMA16(ka[t][1], qf[nt][1], MFMA16(ka[t][0], qf[nt][0], FZ)); \
    bf16x8 pb[2];                                                               \
    _Pragma("unroll")                                                           \
    for (int nt = 0; nt < 2; ++nt) {                                            \
      float p[8];                                                               \
      _Pragma("unroll")                                                         \
      for (int t = 0; t < 2; ++t)                                               \
        _Pragma("unroll")                                                       \
        for (int r = 0; r < 4; ++r) p[t * 4 + r] = __builtin_amdgcn_exp2f(st[nt][t][r]); \
      union { __hip_bfloat162 h2[4]; bf16x8 v8; } u;                            \
      u.h2[0] = __float22bfloat162_rn(float2{p[0], p[1]});                      \
      u.h2[1] = __float22bfloat162_rn(float2{p[2], p[3]});                      \
      u.h2[2] = __float22bfloat162_rn(float2{p[4], p[5]});                      \
      u.h2[3] = __float22bfloat162_rn(float2{p[6], p[7]});                      \
      pb[nt] = u.v8;                                                            \
    }                                                                           \
    _Pragma("unroll")                                                           \
    for (int nt = 0; nt < 2; ++nt) {                                            \
      lacc[nt] = MFMA16(ones, pb[nt], lacc[nt]);                                \
      _Pragma("unroll")                                                         \
      for (int dt = 0; dt < 4; ++dt)                                            \
        o[nt][dt] = MFMA16(vf[dt], pb[nt], o[nt][dt]);                          \
    }                                                                           \
  } while (0)

  for (int it = 0; it < 64; ++it) {
    __syncthreads();   // drains this wave's staging (vmcnt) + block-wide sync

    if (it != 63) {    // stage next pair into the other 16KB half
      const short* gs = sg + (size_t)(2 * it + 2) * 4096;
      short* ld = &sKV[(it + 1) & 1][ldw];
      stage16(gs, ld);
      stage16(gs + 512, ld + 512);
      stage16(gs + 4096, ld + 4096);
      stage16(gs + 4608, ld + 4608);
    }

    const short* S0 = sKV[it & 1];
    const short* S1 = S0 + 4096;
    COMPUTE(S0);       // two independent chains; compiler interleaves
    COMPUTE(S1);
  }
#undef COMPUTE

  // epilogue: every lane of lacc[nt] holds the full row-sum for qrow=l15
  const int b = bh >> 3, h = bh & 7;
#pragma unroll
  for (int nt = 0; nt < 2; ++nt) {
    const float inv = 1.0f / lacc[nt][0];
    const int row = qrow0 + nt * 16 + l15;
    short* cp = ctx + (size_t)(b * 4096 + row) * 512 + h * 64 + quad * 4;
#pragma unroll
    for (int dt = 0; dt < 4; ++dt) {
      union { __hip_bfloat162 h2[2]; shortx4 s4; } u;
      u.h2[0] = __float22bfloat162_rn(float2{o[nt][dt][0] * inv, o[nt][dt][1] * inv});
      u.h2[1] = __float22bfloat162_rn(float2{o[nt][dt][2] * inv, o[nt][dt][3] * inv});
      *(shortx4*)(cp + dt * 16) = u.s4;
    }
  }
}

// ---------------------------------------------------------------------------
extern "C" void kernel_launch(void* const* d_in, const int* in_sizes, int n_in,
                              void* d_out, int out_size, void* d_ws, size_t ws_size,
                              hipStream_t stream) {
  const float* q  = (const float*)d_in[0];
  const float* k  = (const float*)d_in[1];
  const float* v  = (const float*)d_in[2];
  const float* Wq = (const float*)d_in[3];
  const float* bq = (const float*)d_in[4];
  const float* Wk = (const float*)d_in[5];
  const float* bk = (const float*)d_in[6];
  const float* Wv = (const float*)d_in[7];
  const float* bv = (const float*)d_in[8];
  const float* Wo = (const float*)d_in[9];
  const float* bo = (const float*)d_in[10];

  const int XN = 2 * 4096 * 512;
  const int WN = 512 * 512;

  short* ws  = (short*)d_ws;
  short* xqb = ws;                       // q/k/v bf16 (contiguous for cvt3)
  short* xkb = ws + (size_t)XN;
  short* xvb = ws + (size_t)2 * XN;
  short* wqb = ws + (size_t)3 * XN;      // weights bf16 (contiguous for cvtw)
  short* wkb = wqb + WN;
  short* wvb = wkb + WN;
  short* wob = wvb + WN;
  short* Qh  = wob + WN;
  short* KVf = Qh + (size_t)XN;          // fragment-ordered K+V: 2*XN shorts
  short* ctx = xqb;                      // xq dead after projections

  dim3 cg(XN / 4 / 256, 3);
  cvt3_kernel<<<cg, 256, 0, stream>>>(q, k, v, xqb, XN / 4);
  dim3 wg(WN / 4 / 256, 4);
  cvtw_kernel<<<wg, 256, 0, stream>>>(Wq, Wk, Wv, Wo, wqb, WN / 4);

  dim3 pg(64, 8, 3);
  proj3_kernel<<<pg, 256, 0, stream>>>(xqb, xkb, xvb, wqb, wkb, wvb,
                                       bq, bk, bv, Qh, KVf);

  flash_kernel<<<512, 256, 0, stream>>>(Qh, KVf, ctx);

  dim3 og(64, 8);
  proj_o_kernel<<<og, 256, 0, stream>>>(ctx, wob, bo, (float*)d_out);
}